// Round 10
// baseline (1113.023 us; speedup 1.0000x reference)
//
#include <hip/hip_runtime.h>

// B(derived), IN_DIM=784, NUM_NETS=30, N_NODES=20, NUM_OUT=10, DIM_OUT=16, NUM_ITER=3
// Validated: size-based binding; dtype detection; k1m MFMA layouts; k2s; routing math.
// R10: k3 remap thread=(o,k), priors[g][n] in VGPRs, LDS 83KB -> 4.8KB (SP eliminated).
// ws: h1u[B*600] f32 | rwt[96000] f32 | b1f[640] f32 | flags[8] | Wt[640*800] bf16 | xb[B*800] bf16

typedef unsigned short bfu;
typedef unsigned int u32;
typedef __attribute__((ext_vector_type(8))) short short8;
typedef __attribute__((ext_vector_type(4))) float floatx4;

__device__ __forceinline__ float bf2f(bfu u) { union { u32 i; float f; } v; v.i = ((u32)u) << 16; return v.f; }
__device__ __forceinline__ float ldf(const void* p, int idx, bool b16) {
    return b16 ? bf2f(((const bfu*)p)[idx]) : ((const float*)p)[idx];
}
__device__ __forceinline__ bfu f2bf(float f) {   // RNE
    u32 u = __float_as_uint(f);
    return (bfu)((u + 0x7FFFu + ((u >> 16) & 1u)) >> 16);
}

// ---- dtype detector (validated) ----
__global__ void detect_dtype(const u32* x, const u32* W1, const u32* b1,
                             const u32* W2, const u32* b2, const u32* rw,
                             u32* flags) {
    int t = threadIdx.x;
    if (t >= 6) return;
    const u32* p = (t == 0) ? x : (t == 1) ? W1 : (t == 2) ? b1
                 : (t == 3) ? W2 : (t == 4) ? b2 : rw;
    int c = 0;
    for (int i = 0; i < 64; i++) {
        u32 e = (p[i] >> 7) & 0xFF;
        c += (e >= 64 && e <= 140) ? 1 : 0;
    }
    flags[t] = (c >= 48) ? 1u : 0u;
}

// ---- prep: x -> xb[B][800] bf16 (validated) ----
__global__ void prep_xb(const void* x, bfu* __restrict__ xb, const u32* flags, int total) {
    const bool b16 = flags[0] != 0;
    int idx = blockIdx.x * 256 + threadIdx.x;
    if (idx >= total) return;
    int b = idx / 800, kk = idx - b * 800;
    bfu v = 0;
    if (kk < 784) {
        int src = b * 784 + kk;
        v = b16 ? ((const bfu*)x)[src] : f2bf(((const float*)x)[src]);
    }
    xb[idx] = v;
}

// ---- prep: W1[n][k][o] -> Wt[c][k] bf16 (validated) ----
__global__ void prep_wt(const void* W1, bfu* __restrict__ Wt, const u32* flags) {
    const bool wb = flags[1] != 0;
    int idx = blockIdx.x * 256 + threadIdx.x;
    if (idx >= 640 * 800) return;
    int c = idx / 800, k = idx - c * 800;
    bfu v = 0;
    if (c < 600 && k < 784) {
        int nn = c / 20, o = c - nn * 20;
        int src = nn * 15680 + k * 20 + o;
        v = wb ? ((const bfu*)W1)[src] : f2bf(((const float*)W1)[src]);
    }
    Wt[idx] = v;
}

// ---- prep: b1 -> fp32[640] (validated) ----
__global__ void prep_b1(const void* b1, float* __restrict__ b1f, const u32* flags) {
    int i = threadIdx.x;
    if (i >= 640) return;
    b1f[i] = (i < 600) ? ldf(b1, i, flags[2] != 0) : 0.f;
}

// ---- prep: rw[o][n][d][k] -> rwt[o][n][k][d] fp32 (validated) ----
__global__ void prep_rwt(const void* rw, float* __restrict__ rwt, const u32* flags) {
    const bool rb = flags[5] != 0;
    int idx = blockIdx.x * 256 + threadIdx.x;
    if (idx >= 96000) return;
    int d = idx % 20;
    int k = (idx / 20) % 16;
    int n = (idx / 320) % 30;
    int o = idx / 9600;
    rwt[idx] = ldf(rw, o * 9600 + n * 320 + d * 16 + k, rb);
}

// ---------------- K1m: h1 = relu(xb @ Wt^T + b1), bf16 MFMA (validated) ----------------
__global__ __launch_bounds__(256, 4) void k1m(const bfu* __restrict__ xb, const bfu* __restrict__ Wt,
                                              const float* __restrict__ b1f,
                                              float* __restrict__ h1, int Btot) {
    __shared__ short As[128 * 40];
    __shared__ short Bs[64 * 40];
    const int tid = threadIdx.x;
    const int w = tid >> 6, lane = tid & 63;
    const int quad = lane >> 4, fl = lane & 15;
    const int m0 = blockIdx.x * 128, n0 = blockIdx.y * 64;

    floatx4 acc[2][4];
    #pragma unroll
    for (int mi = 0; mi < 2; mi++)
        #pragma unroll
        for (int ni = 0; ni < 4; ni++) acc[mi][ni] = (floatx4){0.f, 0.f, 0.f, 0.f};

    const int arow = tid >> 1, aseg = tid & 1;
    const int brow = tid >> 2, bseg = tid & 3;
    int agrow = m0 + arow; if (agrow >= Btot) agrow = Btot - 1;
    const bfu* abase = xb + (size_t)agrow * 800 + aseg * 16;
    const bfu* bbase = Wt + (size_t)(n0 + brow) * 800 + bseg * 8;

    for (int k0 = 0; k0 < 800; k0 += 32) {
        uint4 qa0 = *(const uint4*)(abase + k0);
        uint4 qa1 = *(const uint4*)(abase + k0 + 8);
        uint4 qb  = *(const uint4*)(bbase + k0);

        __syncthreads();
        *(uint4*)&As[arow * 40 + aseg * 16 + 0] = qa0;
        *(uint4*)&As[arow * 40 + aseg * 16 + 8] = qa1;
        *(uint4*)&Bs[brow * 40 + bseg * 8] = qb;
        __syncthreads();

        short8 af[2], bfr[4];
        #pragma unroll
        for (int mi = 0; mi < 2; mi++)
            af[mi] = *(const short8*)&As[(w * 32 + mi * 16 + fl) * 40 + quad * 8];
        #pragma unroll
        for (int ni = 0; ni < 4; ni++)
            bfr[ni] = *(const short8*)&Bs[(ni * 16 + fl) * 40 + quad * 8];
        #pragma unroll
        for (int mi = 0; mi < 2; mi++)
            #pragma unroll
            for (int ni = 0; ni < 4; ni++)
                acc[mi][ni] = __builtin_amdgcn_mfma_f32_16x16x32_bf16(af[mi], bfr[ni], acc[mi][ni], 0, 0, 0);
    }

    #pragma unroll
    for (int mi = 0; mi < 2; mi++) {
        #pragma unroll
        for (int ni = 0; ni < 4; ni++) {
            const int c = n0 + ni * 16 + fl;
            #pragma unroll
            for (int r = 0; r < 4; r++) {
                const int m = m0 + w * 32 + mi * 16 + quad * 4 + r;
                if (c < 600 && m < Btot)
                    h1[(size_t)m * 600 + c] = fmaxf(acc[mi][ni][r] + b1f[c], 0.f);
            }
        }
    }
}

// ---------------- K2s: u = squash(relu(h1 @ W2 + b2)), LDS-staged W2 (validated) ----------------
__global__ __launch_bounds__(256) void k2s(const float* h1, const void* W2, const void* b2,
                                           float* u, const u32* flags, int total) {
    __shared__ float W2s[12000];
    __shared__ float b2s[600];
    const bool wb = flags[3] != 0, bb = flags[4] != 0;
    const int tid = threadIdx.x;
    for (int i = tid; i < 12000; i += 256) W2s[i] = ldf(W2, i, wb);
    for (int i = tid; i < 600; i += 256) b2s[i] = ldf(b2, i, bb);
    __syncthreads();

    int t = blockIdx.x * 256 + tid;
    if (t >= total) return;          // t = b*30 + n
    const int b = t / 30, n = t - b * 30;
    const float* hp = h1 + (size_t)b * 600 + n * 20;
    float h[20];
    #pragma unroll
    for (int d4 = 0; d4 < 20; d4 += 4) {
        float4 v = *(const float4*)(hp + d4);
        h[d4] = v.x; h[d4 + 1] = v.y; h[d4 + 2] = v.z; h[d4 + 3] = v.w;
    }
    const float* wn = &W2s[n * 400];
    float o[20];
    float sq = 0.f;
    #pragma unroll
    for (int e = 0; e < 20; e++) {
        float acc = b2s[n * 20 + e];
        #pragma unroll
        for (int d = 0; d < 20; d++) acc += h[d] * wn[d * 20 + e];
        acc = fmaxf(acc, 0.f);
        o[e] = acc;
        sq += acc * acc;
    }
    float sc = (sq > 0.f) ? sqrtf(sq) / (1.f + sq) : 0.f;
    float* up = u + (size_t)b * 600 + n * 20;
    #pragma unroll
    for (int e4 = 0; e4 < 20; e4 += 4) {
        float4 v;
        v.x = o[e4] * sc; v.y = o[e4 + 1] * sc; v.z = o[e4 + 2] * sc; v.w = o[e4 + 3] * sc;
        *(float4*)(up + e4) = v;
    }
}

// ---------------- K3x: priors + routing; thread=(o,k), priors in VGPRs, 4.8KB LDS ----------------
// 160 thr/block, 2 batches/block. pri[g][n] per thread (60 VGPRs). No SP array:
// s = sum_n P[n][o]*pri is thread-local. L (logits) + P (probs) in LDS, 600 f each.
__global__ __launch_bounds__(160) void k3x(const float* __restrict__ u,
                                           const float* __restrict__ rwt,
                                           float* __restrict__ out, int Btot) {
    __shared__ float L[2][300];   // [g][n*10+o]
    __shared__ float P[2][300];   // softmax probs
    const int tid = threadIdx.x;  // 0..159
    const int o = tid >> 4, k = tid & 15;
    const int b0 = blockIdx.x * 2;

    int bidx[2];
    #pragma unroll
    for (int g = 0; g < 2; g++) { int b = b0 + g; bidx[g] = (b < Btot) ? b : (Btot - 1); }

    // ---- priors: pri[g][n] = sum_d u[b][n][d] * rwt[o][n][k][d] ----
    float pri[2][30];
    const float* rwb = rwt + o * 9600 + k * 20;   // ((o*30+n)*16+k)*20 = o*9600 + n*320 + k*20
    #pragma unroll
    for (int n = 0; n < 30; n++) {
        float a0 = 0.f, a1 = 0.f;
        #pragma unroll
        for (int d4 = 0; d4 < 5; d4++) {
            float4 rv = *(const float4*)(rwb + n * 320 + d4 * 4);
            float4 u0 = *(const float4*)(u + (size_t)bidx[0] * 600 + n * 20 + d4 * 4);
            float4 u1 = *(const float4*)(u + (size_t)bidx[1] * 600 + n * 20 + d4 * 4);
            a0 += rv.x * u0.x + rv.y * u0.y + rv.z * u0.z + rv.w * u0.w;
            a1 += rv.x * u1.x + rv.y * u1.y + rv.z * u1.z + rv.w * u1.w;
        }
        pri[0][n] = a0; pri[1][n] = a1;
    }

    // init logits
    for (int i = tid; i < 600; i += 160) L[i / 300][i - (i / 300) * 300] = 0.f;
    __syncthreads();

    float v[2];
    for (int it = 0; it < 3; it++) {
        // phase A: P[g][n][o'] = softmax_o'(L[g][n][:]) by 60 threads (g=tid/30, n=tid%30)
        if (tid < 60) {
            const int g = tid / 30, n = tid - (tid / 30) * 30;
            float mx = L[g][n * 10];
            #pragma unroll
            for (int oo = 1; oo < 10; oo++) mx = fmaxf(mx, L[g][n * 10 + oo]);
            float e[10], den = 0.f;
            #pragma unroll
            for (int oo = 0; oo < 10; oo++) { e[oo] = __expf(L[g][n * 10 + oo] - mx); den += e[oo]; }
            float inv = 1.f / den;
            #pragma unroll
            for (int oo = 0; oo < 10; oo++) P[g][n * 10 + oo] = e[oo] * inv;
        }
        __syncthreads();
        // phase B: s (thread-local over n), squash over k (shfl-16)
        #pragma unroll
        for (int g = 0; g < 2; g++) {
            float s = 0.f;
            #pragma unroll
            for (int n = 0; n < 30; n++) s += P[g][n * 10 + o] * pri[g][n];
            float q = s * s;
            q += __shfl_xor(q, 1, 16);
            q += __shfl_xor(q, 2, 16);
            q += __shfl_xor(q, 4, 16);
            q += __shfl_xor(q, 8, 16);
            v[g] = s * sqrtf(q) / (1.f + q);
        }
        if (it < 2) {
            // phase C: L[g][n][o] += sum_k pri*v (shfl-16 butterfly, k==0 lane writes)
            #pragma unroll
            for (int g = 0; g < 2; g++) {
                #pragma unroll
                for (int n = 0; n < 30; n++) {
                    float t = pri[g][n] * v[g];
                    t += __shfl_xor(t, 1, 16);
                    t += __shfl_xor(t, 2, 16);
                    t += __shfl_xor(t, 4, 16);
                    t += __shfl_xor(t, 8, 16);
                    if (k == 0) L[g][n * 10 + o] += t;
                }
            }
            __syncthreads();
        } else {
            #pragma unroll
            for (int g = 0; g < 2; g++)
                if ((b0 + g) < Btot) out[(size_t)(b0 + g) * 160 + (o << 4) + k] = v[g];
        }
    }
}

extern "C" void kernel_launch(void* const* d_in, const int* in_sizes, int n_in,
                              void* d_out, int out_size, void* d_ws, size_t ws_size,
                              hipStream_t stream) {
    // ---- size-based input matching (validated) ----
    int ix = -1, iw1 = -1, ib1 = -1, iw2 = -1, ib2 = -1, irw = -1;
    for (int i = 0; i < n_in; i++) {
        int s = in_sizes[i];
        if (s == 470400 && iw1 < 0) iw1 = i;
        else if (s == 12000 && iw2 < 0) iw2 = i;
        else if (s == 96000 && irw < 0) irw = i;
        else if (s == 600) { if (ib1 < 0) ib1 = i; else if (ib2 < 0) ib2 = i; }
    }
    long bestsz = -1;
    for (int i = 0; i < n_in; i++) {
        if (i == iw1 || i == iw2 || i == irw || i == ib1 || i == ib2) continue;
        if ((long)in_sizes[i] > bestsz) { bestsz = in_sizes[i]; ix = i; }
    }
    if (ix < 0 || iw1 < 0 || ib1 < 0 || iw2 < 0 || ib2 < 0 || irw < 0) {
        ix = 0; iw1 = 1; ib1 = 2; iw2 = 3; ib2 = 4; irw = 5;
    }
    const void* x  = d_in[ix];
    const void* W1 = d_in[iw1];
    const void* b1 = d_in[ib1];
    const void* W2 = d_in[iw2];
    const void* b2 = d_in[ib2];
    const void* rw = d_in[irw];
    const int B = in_sizes[ix] / 784;
    float* out = (float*)d_out;

    float* ws   = (float*)d_ws;
    float* h1u  = ws;                                  // B*600 f32
    float* rwt  = ws + (size_t)B * 600;                // 96000 f32
    float* b1f  = rwt + 96000;                         // 640 f32
    u32*   flags = (u32*)(b1f + 640);                  // 8 u32
    bfu*   Wt   = (bfu*)(flags + 8);                   // 640*800 bf16
    bfu*   xb   = Wt + 640 * 800;                      // B*800 bf16

    detect_dtype<<<1, 64, 0, stream>>>((const u32*)x, (const u32*)W1, (const u32*)b1,
                                       (const u32*)W2, (const u32*)b2, (const u32*)rw, flags);
    prep_xb<<<(B * 800 + 255) / 256, 256, 0, stream>>>(x, xb, flags, B * 800);
    prep_wt<<<(640 * 800 + 255) / 256, 256, 0, stream>>>(W1, Wt, flags);
    prep_b1<<<1, 640, 0, stream>>>(b1, b1f, flags);
    prep_rwt<<<(96000 + 255) / 256, 256, 0, stream>>>(rw, rwt, flags);
    k1m<<<dim3((B + 127) / 128, 10), 256, 0, stream>>>(xb, Wt, b1f, h1u, B);
    k2s<<<(B * 30 + 255) / 256, 256, 0, stream>>>(h1u, W2, b2, h1u, flags, B * 30);
    k3x<<<(B + 1) / 2, 160, 0, stream>>>(h1u, rwt, out, B);
}

// Round 11
// 357.549 us; speedup vs baseline: 3.1129x; 3.1129x over previous
//
#include <hip/hip_runtime.h>

// B(derived), IN_DIM=784, NUM_NETS=30, N_NODES=20, NUM_OUT=10, DIM_OUT=16, NUM_ITER=3
// Validated: size-based binding; dtype detection; k1m MFMA; k2s; k3 (o,k)-map math.
// R11: fix k3x spill (VGPR 256 + 435MB scratch): g=1 per 160-thr group (pri[30]),
// 4 groups/640-thr block, u staged in LDS, bounded unroll. LDS 14.4KB/block.
// ws: h1u[B*600] f32 | rwt[96000] f32 | b1f[640] f32 | flags[8] | Wt[640*800] bf16 | xb[B*800] bf16

typedef unsigned short bfu;
typedef unsigned int u32;
typedef __attribute__((ext_vector_type(8))) short short8;
typedef __attribute__((ext_vector_type(4))) float floatx4;

__device__ __forceinline__ float bf2f(bfu u) { union { u32 i; float f; } v; v.i = ((u32)u) << 16; return v.f; }
__device__ __forceinline__ float ldf(const void* p, int idx, bool b16) {
    return b16 ? bf2f(((const bfu*)p)[idx]) : ((const float*)p)[idx];
}
__device__ __forceinline__ bfu f2bf(float f) {   // RNE
    u32 u = __float_as_uint(f);
    return (bfu)((u + 0x7FFFu + ((u >> 16) & 1u)) >> 16);
}

// ---- dtype detector (validated) ----
__global__ void detect_dtype(const u32* x, const u32* W1, const u32* b1,
                             const u32* W2, const u32* b2, const u32* rw,
                             u32* flags) {
    int t = threadIdx.x;
    if (t >= 6) return;
    const u32* p = (t == 0) ? x : (t == 1) ? W1 : (t == 2) ? b1
                 : (t == 3) ? W2 : (t == 4) ? b2 : rw;
    int c = 0;
    for (int i = 0; i < 64; i++) {
        u32 e = (p[i] >> 7) & 0xFF;
        c += (e >= 64 && e <= 140) ? 1 : 0;
    }
    flags[t] = (c >= 48) ? 1u : 0u;
}

// ---- prep: x -> xb[B][800] bf16 (validated) ----
__global__ void prep_xb(const void* x, bfu* __restrict__ xb, const u32* flags, int total) {
    const bool b16 = flags[0] != 0;
    int idx = blockIdx.x * 256 + threadIdx.x;
    if (idx >= total) return;
    int b = idx / 800, kk = idx - b * 800;
    bfu v = 0;
    if (kk < 784) {
        int src = b * 784 + kk;
        v = b16 ? ((const bfu*)x)[src] : f2bf(((const float*)x)[src]);
    }
    xb[idx] = v;
}

// ---- prep: W1[n][k][o] -> Wt[c][k] bf16 (validated) ----
__global__ void prep_wt(const void* W1, bfu* __restrict__ Wt, const u32* flags) {
    const bool wb = flags[1] != 0;
    int idx = blockIdx.x * 256 + threadIdx.x;
    if (idx >= 640 * 800) return;
    int c = idx / 800, k = idx - c * 800;
    bfu v = 0;
    if (c < 600 && k < 784) {
        int nn = c / 20, o = c - nn * 20;
        int src = nn * 15680 + k * 20 + o;
        v = wb ? ((const bfu*)W1)[src] : f2bf(((const float*)W1)[src]);
    }
    Wt[idx] = v;
}

// ---- prep: b1 -> fp32[640] (validated) ----
__global__ void prep_b1(const void* b1, float* __restrict__ b1f, const u32* flags) {
    int i = threadIdx.x;
    if (i >= 640) return;
    b1f[i] = (i < 600) ? ldf(b1, i, flags[2] != 0) : 0.f;
}

// ---- prep: rw[o][n][d][k] -> rwt[o][n][k][d] fp32 (validated) ----
__global__ void prep_rwt(const void* rw, float* __restrict__ rwt, const u32* flags) {
    const bool rb = flags[5] != 0;
    int idx = blockIdx.x * 256 + threadIdx.x;
    if (idx >= 96000) return;
    int d = idx % 20;
    int k = (idx / 20) % 16;
    int n = (idx / 320) % 30;
    int o = idx / 9600;
    rwt[idx] = ldf(rw, o * 9600 + n * 320 + d * 16 + k, rb);
}

// ---------------- K1m: h1 = relu(xb @ Wt^T + b1), bf16 MFMA (validated) ----------------
__global__ __launch_bounds__(256, 4) void k1m(const bfu* __restrict__ xb, const bfu* __restrict__ Wt,
                                              const float* __restrict__ b1f,
                                              float* __restrict__ h1, int Btot) {
    __shared__ short As[128 * 40];
    __shared__ short Bs[64 * 40];
    const int tid = threadIdx.x;
    const int w = tid >> 6, lane = tid & 63;
    const int quad = lane >> 4, fl = lane & 15;
    const int m0 = blockIdx.x * 128, n0 = blockIdx.y * 64;

    floatx4 acc[2][4];
    #pragma unroll
    for (int mi = 0; mi < 2; mi++)
        #pragma unroll
        for (int ni = 0; ni < 4; ni++) acc[mi][ni] = (floatx4){0.f, 0.f, 0.f, 0.f};

    const int arow = tid >> 1, aseg = tid & 1;
    const int brow = tid >> 2, bseg = tid & 3;
    int agrow = m0 + arow; if (agrow >= Btot) agrow = Btot - 1;
    const bfu* abase = xb + (size_t)agrow * 800 + aseg * 16;
    const bfu* bbase = Wt + (size_t)(n0 + brow) * 800 + bseg * 8;

    for (int k0 = 0; k0 < 800; k0 += 32) {
        uint4 qa0 = *(const uint4*)(abase + k0);
        uint4 qa1 = *(const uint4*)(abase + k0 + 8);
        uint4 qb  = *(const uint4*)(bbase + k0);

        __syncthreads();
        *(uint4*)&As[arow * 40 + aseg * 16 + 0] = qa0;
        *(uint4*)&As[arow * 40 + aseg * 16 + 8] = qa1;
        *(uint4*)&Bs[brow * 40 + bseg * 8] = qb;
        __syncthreads();

        short8 af[2], bfr[4];
        #pragma unroll
        for (int mi = 0; mi < 2; mi++)
            af[mi] = *(const short8*)&As[(w * 32 + mi * 16 + fl) * 40 + quad * 8];
        #pragma unroll
        for (int ni = 0; ni < 4; ni++)
            bfr[ni] = *(const short8*)&Bs[(ni * 16 + fl) * 40 + quad * 8];
        #pragma unroll
        for (int mi = 0; mi < 2; mi++)
            #pragma unroll
            for (int ni = 0; ni < 4; ni++)
                acc[mi][ni] = __builtin_amdgcn_mfma_f32_16x16x32_bf16(af[mi], bfr[ni], acc[mi][ni], 0, 0, 0);
    }

    #pragma unroll
    for (int mi = 0; mi < 2; mi++) {
        #pragma unroll
        for (int ni = 0; ni < 4; ni++) {
            const int c = n0 + ni * 16 + fl;
            #pragma unroll
            for (int r = 0; r < 4; r++) {
                const int m = m0 + w * 32 + mi * 16 + quad * 4 + r;
                if (c < 600 && m < Btot)
                    h1[(size_t)m * 600 + c] = fmaxf(acc[mi][ni][r] + b1f[c], 0.f);
            }
        }
    }
}

// ---------------- K2s: u = squash(relu(h1 @ W2 + b2)), LDS-staged W2 (validated) ----------------
__global__ __launch_bounds__(256) void k2s(const float* h1, const void* W2, const void* b2,
                                           float* u, const u32* flags, int total) {
    __shared__ float W2s[12000];
    __shared__ float b2s[600];
    const bool wb = flags[3] != 0, bb = flags[4] != 0;
    const int tid = threadIdx.x;
    for (int i = tid; i < 12000; i += 256) W2s[i] = ldf(W2, i, wb);
    for (int i = tid; i < 600; i += 256) b2s[i] = ldf(b2, i, bb);
    __syncthreads();

    int t = blockIdx.x * 256 + tid;
    if (t >= total) return;          // t = b*30 + n
    const int b = t / 30, n = t - b * 30;
    const float* hp = h1 + (size_t)b * 600 + n * 20;
    float h[20];
    #pragma unroll
    for (int d4 = 0; d4 < 20; d4 += 4) {
        float4 v = *(const float4*)(hp + d4);
        h[d4] = v.x; h[d4 + 1] = v.y; h[d4 + 2] = v.z; h[d4 + 3] = v.w;
    }
    const float* wn = &W2s[n * 400];
    float o[20];
    float sq = 0.f;
    #pragma unroll
    for (int e = 0; e < 20; e++) {
        float acc = b2s[n * 20 + e];
        #pragma unroll
        for (int d = 0; d < 20; d++) acc += h[d] * wn[d * 20 + e];
        acc = fmaxf(acc, 0.f);
        o[e] = acc;
        sq += acc * acc;
    }
    float sc = (sq > 0.f) ? sqrtf(sq) / (1.f + sq) : 0.f;
    float* up = u + (size_t)b * 600 + n * 20;
    #pragma unroll
    for (int e4 = 0; e4 < 20; e4 += 4) {
        float4 v;
        v.x = o[e4] * sc; v.y = o[e4 + 1] * sc; v.z = o[e4 + 2] * sc; v.w = o[e4 + 3] * sc;
        *(float4*)(up + e4) = v;
    }
}

// ---------------- K3y: routing; 4 groups x 160 thr, 1 batch/group, pri[30] in VGPRs ----------------
// Same math as validated k3x, register-economized: u in LDS, bounded unroll, g=1.
__global__ __launch_bounds__(640, 2) void k3y(const float* __restrict__ u,
                                              const float* __restrict__ rwt,
                                              float* __restrict__ out, int Btot) {
    __shared__ float US[4][600];   // staged u per group
    __shared__ float L[4][300];    // logits [g][n*10+o]
    __shared__ float P[4][300];    // softmax probs
    const int tid = threadIdx.x;
    const int g = tid / 160, r = tid - g * 160;   // group, local id
    const int o = r >> 4, k = r & 15;
    const int b0 = blockIdx.x * 4;

    // stage u (coalesced float4) + init logits
    {
        const int nf4 = 600 / 4;   // 150 float4 per group, 600 total
        for (int i = tid; i < 4 * nf4; i += 640) {
            int gg = i / nf4, j = i - gg * nf4;
            int bb = b0 + gg; if (bb >= Btot) bb = Btot - 1;
            *(float4*)&US[gg][j * 4] = *(const float4*)(u + (size_t)bb * 600 + j * 4);
        }
        for (int i = tid; i < 1200; i += 640) L[i / 300][i % 300] = 0.f;
    }
    __syncthreads();

    // priors: pri[n] = sum_d US[g][n*20+d] * rwt[o][n][k][d]
    float pri[30];
    const float* rwb = rwt + o * 9600 + k * 20;
    #pragma unroll 3
    for (int n = 0; n < 30; n++) {
        const float4* rp = (const float4*)(rwb + n * 320);
        float a = 0.f;
        #pragma unroll
        for (int d4 = 0; d4 < 5; d4++) {
            float4 rv = rp[d4];
            float4 uu = *(const float4*)&US[g][n * 20 + d4 * 4];
            a += rv.x * uu.x + rv.y * uu.y + rv.z * uu.z + rv.w * uu.w;
        }
        pri[n] = a;
    }

    float v = 0.f;
    for (int it = 0; it < 3; it++) {
        // phase A: P[g][n][:] = softmax(L[g][n][:]) by r<30 (n=r) per group
        if (r < 30) {
            const int n = r;
            float mx = L[g][n * 10];
            #pragma unroll
            for (int oo = 1; oo < 10; oo++) mx = fmaxf(mx, L[g][n * 10 + oo]);
            float e[10], den = 0.f;
            #pragma unroll
            for (int oo = 0; oo < 10; oo++) { e[oo] = __expf(L[g][n * 10 + oo] - mx); den += e[oo]; }
            float inv = 1.f / den;
            #pragma unroll
            for (int oo = 0; oo < 10; oo++) P[g][n * 10 + oo] = e[oo] * inv;
        }
        __syncthreads();
        // phase B: s thread-local over n; squash over k (shfl-16)
        float s = 0.f;
        #pragma unroll
        for (int n = 0; n < 30; n++) s += P[g][n * 10 + o] * pri[n];
        float q = s * s;
        q += __shfl_xor(q, 1, 16);
        q += __shfl_xor(q, 2, 16);
        q += __shfl_xor(q, 4, 16);
        q += __shfl_xor(q, 8, 16);
        v = s * sqrtf(q) / (1.f + q);
        if (it < 2) {
            // phase C: L[g][n][o] += sum_k pri*v (shfl-16; k==0 lane writes)
            #pragma unroll
            for (int n = 0; n < 30; n++) {
                float t = pri[n] * v;
                t += __shfl_xor(t, 1, 16);
                t += __shfl_xor(t, 2, 16);
                t += __shfl_xor(t, 4, 16);
                t += __shfl_xor(t, 8, 16);
                if (k == 0) L[g][n * 10 + o] += t;
            }
            __syncthreads();   // C-writes visible to next A; B's P-reads done before next A's P-writes
        }
    }
    if ((b0 + g) < Btot) out[(size_t)(b0 + g) * 160 + r] = v;
}

extern "C" void kernel_launch(void* const* d_in, const int* in_sizes, int n_in,
                              void* d_out, int out_size, void* d_ws, size_t ws_size,
                              hipStream_t stream) {
    // ---- size-based input matching (validated) ----
    int ix = -1, iw1 = -1, ib1 = -1, iw2 = -1, ib2 = -1, irw = -1;
    for (int i = 0; i < n_in; i++) {
        int s = in_sizes[i];
        if (s == 470400 && iw1 < 0) iw1 = i;
        else if (s == 12000 && iw2 < 0) iw2 = i;
        else if (s == 96000 && irw < 0) irw = i;
        else if (s == 600) { if (ib1 < 0) ib1 = i; else if (ib2 < 0) ib2 = i; }
    }
    long bestsz = -1;
    for (int i = 0; i < n_in; i++) {
        if (i == iw1 || i == iw2 || i == irw || i == ib1 || i == ib2) continue;
        if ((long)in_sizes[i] > bestsz) { bestsz = in_sizes[i]; ix = i; }
    }
    if (ix < 0 || iw1 < 0 || ib1 < 0 || iw2 < 0 || ib2 < 0 || irw < 0) {
        ix = 0; iw1 = 1; ib1 = 2; iw2 = 3; ib2 = 4; irw = 5;
    }
    const void* x  = d_in[ix];
    const void* W1 = d_in[iw1];
    const void* b1 = d_in[ib1];
    const void* W2 = d_in[iw2];
    const void* b2 = d_in[ib2];
    const void* rw = d_in[irw];
    const int B = in_sizes[ix] / 784;
    float* out = (float*)d_out;

    float* ws   = (float*)d_ws;
    float* h1u  = ws;                                  // B*600 f32
    float* rwt  = ws + (size_t)B * 600;                // 96000 f32
    float* b1f  = rwt + 96000;                         // 640 f32
    u32*   flags = (u32*)(b1f + 640);                  // 8 u32
    bfu*   Wt   = (bfu*)(flags + 8);                   // 640*800 bf16
    bfu*   xb   = Wt + 640 * 800;                      // B*800 bf16

    detect_dtype<<<1, 64, 0, stream>>>((const u32*)x, (const u32*)W1, (const u32*)b1,
                                       (const u32*)W2, (const u32*)b2, (const u32*)rw, flags);
    prep_xb<<<(B * 800 + 255) / 256, 256, 0, stream>>>(x, xb, flags, B * 800);
    prep_wt<<<(640 * 800 + 255) / 256, 256, 0, stream>>>(W1, Wt, flags);
    prep_b1<<<1, 640, 0, stream>>>(b1, b1f, flags);
    prep_rwt<<<(96000 + 255) / 256, 256, 0, stream>>>(rw, rwt, flags);
    k1m<<<dim3((B + 127) / 128, 10), 256, 0, stream>>>(xb, Wt, b1f, h1u, B);
    k2s<<<(B * 30 + 255) / 256, 256, 0, stream>>>(h1u, W2, b2, h1u, flags, B * 30);
    k3y<<<(B + 3) / 4, 640, 0, stream>>>(h1u, rwt, out, B);
}